// Round 7
// baseline (168.003 us; speedup 1.0000x reference)
//
#include <hip/hip_runtime.h>

#define TSTEPS 64
#define NI 8192
#define NO 8192
#define DECAY 0.9375f
#define NDET 64               // detect blocks

typedef __attribute__((ext_vector_type(8))) short bf16x8;   // MFMA A/B frag (4 VGPR)
typedef __attribute__((ext_vector_type(4))) float f32x4;    // MFMA C/D frag

// ---------------------------------------------------------------------------
// Kernel 0 (verbatim, passing): detect uint8 vs int32 spike storage.
// ---------------------------------------------------------------------------
__global__ __launch_bounds__(256) void detect_kernel(const unsigned int* sp, int* flags) {
    __shared__ int any;
    if (threadIdx.x == 0) any = 0;
    __syncthreads();
    int local = 0;
    const unsigned int* p = sp + blockIdx.x * 2048;       // 8 KB per block
    #pragma unroll
    for (int i = 0; i < 8; ++i) {
        unsigned int w = p[i * 256 + threadIdx.x];
        if (w & 0xFFFFFF00u) local = 1;
    }
    if (local) atomicOr(&any, 1);
    __syncthreads();
    if (threadIdx.x == 0) flags[blockIdx.x] = any;        // 1 => uint8 layout
}

// ---------------------------------------------------------------------------
// Kernel 1 (verbatim, passing): spikes -> row-major bf16 S[t][k] (1 MB).
// ---------------------------------------------------------------------------
__global__ __launch_bounds__(256) void convert_kernel(const void* sp, const int* flags,
                                                      unsigned short* __restrict__ Sbf) {
    int f = 0;
    for (int i = 0; i < NDET; ++i) f |= flags[i];
    const int gid = blockIdx.x * 256 + threadIdx.x;   // 0..65535
    const int t   = gid >> 10;
    const int k0  = (gid & 1023) * 8;
    unsigned h[8];
    #pragma unroll
    for (int e = 0; e < 8; ++e) {
        int gi = t * NI + k0 + e;
        bool b;
        if (f) b = ((const unsigned char*)sp)[gi] != 0;
        else   b = ((const int*)sp)[gi] != 0;
        h[e] = b ? 0x3F80u : 0u;                      // bf16(1.0) = 0x3F80
    }
    uint4 v;
    v.x = h[0] | (h[1] << 16);
    v.y = h[2] | (h[3] << 16);
    v.z = h[4] | (h[5] << 16);
    v.w = h[6] | (h[7] << 16);
    *(uint4*)(Sbf + (size_t)t * NI + k0) = v;
}

// ---------------------------------------------------------------------------
// Triple split (UNCHANGED, passing): w = hi + mid + lo, error <= 2^-22 |w|.
// ---------------------------------------------------------------------------
__device__ __forceinline__ void split3(const float4& x, const float4& y,
                                       bf16x8& hi, bf16x8& mid, bf16x8& lo) {
    float v[8] = {x.x, x.y, x.z, x.w, y.x, y.y, y.z, y.w};
    #pragma unroll
    for (int e = 0; e < 8; ++e) {
        unsigned b   = __float_as_uint(v[e]);
        unsigned hb  = b & 0xFFFF0000u;
        float    r1  = v[e] - __uint_as_float(hb);                // exact
        unsigned r1b = __float_as_uint(r1);
        unsigned mb  = r1b & 0xFFFF0000u;
        float    r2  = r1 - __uint_as_float(mb);                  // exact
        unsigned r2b = __float_as_uint(r2);
        unsigned lr  = (r2b + 0x7FFFu + ((r2b >> 16) & 1u)) >> 16; // RNE bf16
        hi[e]  = (short)(b >> 16);
        mid[e] = (short)(mb >> 16);
        lo[e]  = (short)lr;
    }
}

// ---------------------------------------------------------------------------
// Kernel 2: FUSED gemm + K-reduce + LIF scan — round-6 structure, schedule
// fixed. Round 6 compiled to a 32-VGPR depth-1 pipeline (latency-bound:
// MfmaUtil 6%, VALUBusy 10%). Now: explicit software pipeline with NAMED
// buffers (static indexing only) — 4 A-buffers (HBM stream, ~3.5 compute
// phases of prefetch) + 2 B-buffers (L2-resident S, 1 phase), 4 chunks per
// unrolled iteration. Prefetch chunk index wraps &31 (tail prefetches hit
// L2-hot chunk 0-3, in-bounds, results unused).
// ---------------------------------------------------------------------------
#define LA(s, cc) do { int _k = ((cc) & 31) * 32;                             \
    a0##s = *(const float4*)(ap + _k);                                        \
    a1##s = *(const float4*)(ap + _k + 4); } while (0)

#define LB(s, cc) do { int _k = ((cc) & 31) * 32;                             \
    b0##s = *(const bf16x8*)(bp0 + _k);                                       \
    b1##s = *(const bf16x8*)(bp1 + _k);                                       \
    b2##s = *(const bf16x8*)(bp2 + _k);                                       \
    b3##s = *(const bf16x8*)(bp3 + _k); } while (0)

#define COMP(sa, sb) do {                                                     \
    bf16x8 hi, mid, lo;                                                       \
    split3(a0##sa, a1##sa, hi, mid, lo);                                      \
    acc0 = __builtin_amdgcn_mfma_f32_16x16x32_bf16(hi,  b0##sb, acc0, 0,0,0); \
    acc0 = __builtin_amdgcn_mfma_f32_16x16x32_bf16(mid, b0##sb, acc0, 0,0,0); \
    acc0 = __builtin_amdgcn_mfma_f32_16x16x32_bf16(lo,  b0##sb, acc0, 0,0,0); \
    acc1 = __builtin_amdgcn_mfma_f32_16x16x32_bf16(hi,  b1##sb, acc1, 0,0,0); \
    acc1 = __builtin_amdgcn_mfma_f32_16x16x32_bf16(mid, b1##sb, acc1, 0,0,0); \
    acc1 = __builtin_amdgcn_mfma_f32_16x16x32_bf16(lo,  b1##sb, acc1, 0,0,0); \
    acc2 = __builtin_amdgcn_mfma_f32_16x16x32_bf16(hi,  b2##sb, acc2, 0,0,0); \
    acc2 = __builtin_amdgcn_mfma_f32_16x16x32_bf16(mid, b2##sb, acc2, 0,0,0); \
    acc2 = __builtin_amdgcn_mfma_f32_16x16x32_bf16(lo,  b2##sb, acc2, 0,0,0); \
    acc3 = __builtin_amdgcn_mfma_f32_16x16x32_bf16(hi,  b3##sb, acc3, 0,0,0); \
    acc3 = __builtin_amdgcn_mfma_f32_16x16x32_bf16(mid, b3##sb, acc3, 0,0,0); \
    acc3 = __builtin_amdgcn_mfma_f32_16x16x32_bf16(lo,  b3##sb, acc3, 0,0,0); \
} while (0)

__global__ __launch_bounds__(512, 4) void fused_kernel(const float* __restrict__ W,
                                                       const unsigned short* __restrict__ Sbf,
                                                       float* __restrict__ out) {
    __shared__ float red[8][16][66];

    const int tid  = threadIdx.x;
    const int w    = tid >> 6;          // wave 0..7 -> K-chunk
    const int lane = tid & 63;
    const int r16  = lane & 15;
    const int kg   = lane >> 4;
    const int o0   = blockIdx.x * 16;
    const int kbase = w * 1024 + kg * 8;

    f32x4 acc0 = (f32x4)0.f, acc1 = (f32x4)0.f, acc2 = (f32x4)0.f, acc3 = (f32x4)0.f;

    const float* ap = W + (size_t)(o0 + r16) * NI + kbase;
    const unsigned short* bp0 = Sbf + (size_t)(r16)      * NI + kbase;
    const unsigned short* bp1 = Sbf + (size_t)(16 + r16) * NI + kbase;
    const unsigned short* bp2 = Sbf + (size_t)(32 + r16) * NI + kbase;
    const unsigned short* bp3 = Sbf + (size_t)(48 + r16) * NI + kbase;

    float4 a0A, a1A, a0B, a1B, a0C, a1C, a0D, a1D;
    bf16x8 b0X, b1X, b2X, b3X, b0Y, b1Y, b2Y, b3Y;

    LA(A, 0); LA(B, 1); LA(C, 2); LA(D, 3);
    LB(X, 0); LB(Y, 1);

    #pragma unroll 1
    for (int c = 0; c < 32; c += 4) {
        COMP(A, X); LA(A, c + 4); LB(X, c + 2);
        COMP(B, Y); LA(B, c + 5); LB(Y, c + 3);
        COMP(C, X); LA(C, c + 6); LB(X, c + 4);
        COMP(D, Y); LA(D, c + 7); LB(Y, c + 5);
    }

    // acc -> LDS per verified D-map: t(col) = n*16 + r16, o = kg*4 + reg.
    // Lane->bank: r16 + 8*kg (mod 32) => exactly 2-way everywhere (free, m136).
    #pragma unroll
    for (int r = 0; r < 4; ++r) {
        red[w][kg * 4 + r][r16]      = acc0[r];
        red[w][kg * 4 + r][16 + r16] = acc1[r];
        red[w][kg * 4 + r][32 + r16] = acc2[r];
        red[w][kg * 4 + r][48 + r16] = acc3[r];
    }
    __syncthreads();

    // Deterministic cross-wave K-reduction: each thread owns 2 (o,t) cells.
    #pragma unroll
    for (int i = tid; i < 1024; i += 512) {
        int o = i >> 6, t = i & 63;
        float s = 0.f;
        #pragma unroll
        for (int w2 = 0; w2 < 8; ++w2) s += red[w2][o][t];
        red[0][o][t] = s;
    }
    __syncthreads();

    // LIF scan: 16 threads, one neuron each, serial in t (inherent).
    if (tid < 16) {
        const int o = tid;
        float m = 0.f;
        out[o0 + o] = 0.f;                               // spike row 0
        #pragma unroll 4
        for (int t = 0; t < TSTEPS; ++t) {
            m += red[0][o][t];
            bool sp = (m >= 1.0f);
            out[(size_t)(t + 1) * NO + o0 + o] = sp ? 1.0f : 0.0f;
            m = sp ? (m - 1.0f) : m * DECAY;
        }
        out[(size_t)(TSTEPS + 1) * NO + o0 + o] = m;     // final mempot
    }
}

// ---------------------------------------------------------------------------
extern "C" void kernel_launch(void* const* d_in, const int* in_sizes, int n_in,
                              void* d_out, int out_size, void* d_ws, size_t ws_size,
                              hipStream_t stream) {
    const void*  spikes = d_in[0];
    const float* W      = (const float*)d_in[1];
    float*       out    = (float*)d_out;
    char*        ws     = (char*)d_ws;

    // ws layout: [flags 256 B][Sbf 1 MB]
    int*            flags = (int*)ws;
    unsigned short* Sbf   = (unsigned short*)(ws + 256);

    hipLaunchKernelGGL(detect_kernel,  dim3(NDET),    dim3(256), 0, stream,
                       (const unsigned int*)spikes, flags);
    hipLaunchKernelGGL(convert_kernel, dim3(256),     dim3(256), 0, stream,
                       spikes, flags, Sbf);
    hipLaunchKernelGGL(fused_kernel,   dim3(NO / 16), dim3(512), 0, stream,
                       W, Sbf, out);
}

// Round 8
// 128.650 us; speedup vs baseline: 1.3059x; 1.3059x over previous
//
#include <hip/hip_runtime.h>

#define TSTEPS 64
#define NI 8192
#define NO 8192
#define DECAY 0.9375f
#define NDET 64               // detect blocks

typedef __attribute__((ext_vector_type(8))) short bf16x8;   // MFMA A/B frag (4 VGPR)
typedef __attribute__((ext_vector_type(4))) float f32x4;    // MFMA C/D frag

// ---------------------------------------------------------------------------
// Kernel 0 (verbatim, passing): detect uint8 vs int32 spike storage.
// ---------------------------------------------------------------------------
__global__ __launch_bounds__(256) void detect_kernel(const unsigned int* sp, int* flags) {
    __shared__ int any;
    if (threadIdx.x == 0) any = 0;
    __syncthreads();
    int local = 0;
    const unsigned int* p = sp + blockIdx.x * 2048;       // 8 KB per block
    #pragma unroll
    for (int i = 0; i < 8; ++i) {
        unsigned int w = p[i * 256 + threadIdx.x];
        if (w & 0xFFFFFF00u) local = 1;
    }
    if (local) atomicOr(&any, 1);
    __syncthreads();
    if (threadIdx.x == 0) flags[blockIdx.x] = any;        // 1 => uint8 layout
}

// ---------------------------------------------------------------------------
// Kernel 1 (verbatim, passing): spikes -> row-major bf16 S[t][k] (1 MB).
// ---------------------------------------------------------------------------
__global__ __launch_bounds__(256) void convert_kernel(const void* sp, const int* flags,
                                                      unsigned short* __restrict__ Sbf) {
    int f = 0;
    for (int i = 0; i < NDET; ++i) f |= flags[i];
    const int gid = blockIdx.x * 256 + threadIdx.x;   // 0..65535
    const int t   = gid >> 10;
    const int k0  = (gid & 1023) * 8;
    unsigned h[8];
    #pragma unroll
    for (int e = 0; e < 8; ++e) {
        int gi = t * NI + k0 + e;
        bool b;
        if (f) b = ((const unsigned char*)sp)[gi] != 0;
        else   b = ((const int*)sp)[gi] != 0;
        h[e] = b ? 0x3F80u : 0u;                      // bf16(1.0) = 0x3F80
    }
    uint4 v;
    v.x = h[0] | (h[1] << 16);
    v.y = h[2] | (h[3] << 16);
    v.z = h[4] | (h[5] << 16);
    v.w = h[6] | (h[7] << 16);
    *(uint4*)(Sbf + (size_t)t * NI + k0) = v;
}

// ---------------------------------------------------------------------------
// Triple split (UNCHANGED, passing): w = hi + mid + lo, error <= 2^-22 |w|.
// ---------------------------------------------------------------------------
__device__ __forceinline__ void split3(const float4& x, const float4& y,
                                       bf16x8& hi, bf16x8& mid, bf16x8& lo) {
    float v[8] = {x.x, x.y, x.z, x.w, y.x, y.y, y.z, y.w};
    #pragma unroll
    for (int e = 0; e < 8; ++e) {
        unsigned b   = __float_as_uint(v[e]);
        unsigned hb  = b & 0xFFFF0000u;
        float    r1  = v[e] - __uint_as_float(hb);                // exact
        unsigned r1b = __float_as_uint(r1);
        unsigned mb  = r1b & 0xFFFF0000u;
        float    r2  = r1 - __uint_as_float(mb);                  // exact
        unsigned r2b = __float_as_uint(r2);
        unsigned lr  = (r2b + 0x7FFFu + ((r2b >> 16) & 1u)) >> 16; // RNE bf16
        hi[e]  = (short)(b >> 16);
        mid[e] = (short)(mb >> 16);
        lo[e]  = (short)lr;
    }
}

// ---------------------------------------------------------------------------
// Async global->LDS DMA, 16 B per lane. LDS dst is wave-uniform base +
// lane*16 (HW rule); global src is per-lane (carries the swizzle).
// ---------------------------------------------------------------------------
__device__ __forceinline__ void gload_lds16(const float* g, float* l) {
    __builtin_amdgcn_global_load_lds(
        (const __attribute__((address_space(1))) void*)g,
        (__attribute__((address_space(3))) void*)l, 16, 0, 0);
}

#define MFMA_BF16 __builtin_amdgcn_mfma_f32_16x16x32_bf16
// Counted wait: chunk c's 12 ops (4 W-DMA + 8 B-loads) drained; chunk c+1's
// 12 stay in flight. Never vmcnt(0) in the loop. sched_barrier pins MFMAs
// from floating above the wait (rule #18).
#define WAITV12() do { asm volatile("s_waitcnt vmcnt(12)" ::: "memory"); \
                       __builtin_amdgcn_sched_barrier(0); } while (0)

// ---------------------------------------------------------------------------
// Kernel 2: FUSED gemm + K-reduce + LIF scan. Round-6 skeleton (passing
// maps/epilogue), K-loop rebuilt on global_load_lds + counted vmcnt:
//  - wave w owns k in [w*1024, w*1024+1024), 16 chunks of 64 k
//  - W chunk staged to private LDS (16x64 f32 = 4 KB, 4 DMA ops), 2 stages
//  - global source XOR-swizzled (u_src = (l&15) ^ (row&7)); ds_read_b128
//    applies the same XOR -> bank-conflict-free (2 lanes/quad per phase)
//  - B (L2-resident S) double-buffered in registers
//  - NO barriers in the main loop; nothing waits to vmcnt(0)
// LDS: 8 waves x 2 stages x 4 KB = 64 KB, aliased by red[8][16][66] after a
// barrier. 512 blocks x 512 threads = 2 blocks/CU (16 waves/CU).
// ---------------------------------------------------------------------------
__global__ __launch_bounds__(512, 4) void fused_kernel(const float* __restrict__ W,
                                                       const unsigned short* __restrict__ Sbf,
                                                       float* __restrict__ out) {
    __shared__ __align__(1024) float lds[16384];   // 64 KB

    const int tid  = threadIdx.x;
    const int w    = tid >> 6;          // wave 0..7 -> K-slice
    const int lane = tid & 63;
    const int r16  = lane & 15;
    const int kg   = lane >> 4;
    const int o0   = blockIdx.x * 16;
    const int wk0  = w * 1024;

    // Per-lane swizzled global W pointers for DMA instruction j (rows 4j..4j+3):
    // lane l -> row 4j + (l>>4), LDS unit (l&15); fetch global unit (l&15)^(row&7)
    // so that LDS[row][u] holds global unit u^(row&7).
    const float* gw[4];
    #pragma unroll
    for (int j = 0; j < 4; ++j) {
        int row  = j * 4 + (lane >> 4);
        int usrc = (lane & 15) ^ (row & 7);
        gw[j] = W + (size_t)(o0 + row) * NI + wk0 + usrc * 4;
    }

    // Per-lane swizzled LDS read byte-offsets: A-frag (row r16, k32-half h,
    // 16-B half) lives at unit (h*8 + kg*2 + half) ^ (r16&7).
    int offA[2][2];
    #pragma unroll
    for (int h = 0; h < 2; ++h)
        #pragma unroll
        for (int hf = 0; hf < 2; ++hf) {
            int u = h * 8 + kg * 2 + hf;
            offA[h][hf] = r16 * 256 + ((u ^ (r16 & 7)) * 16);
        }

    const unsigned short* bp[4];
    #pragma unroll
    for (int n = 0; n < 4; ++n)
        bp[n] = Sbf + (size_t)(n * 16 + r16) * NI + wk0 + kg * 8;

    char* wlds = (char*)lds + w * 8192;            // wave-private 2-stage region

    f32x4 acc[4];
    #pragma unroll
    for (int n = 0; n < 4; ++n) acc[n] = (f32x4)0.f;

    bf16x8 bX[2][4], bY[2][4];

    #define ISSUE_W(cc, stage) do {                                          \
        char* _d = wlds + (stage) * 4096;                                    \
        _Pragma("unroll") for (int j = 0; j < 4; ++j)                        \
            gload_lds16(gw[j] + (cc) * 64, (float*)(_d + j * 1024));         \
    } while (0)

    #define ISSUE_B(BB, cc) do {                                             \
        _Pragma("unroll") for (int h = 0; h < 2; ++h)                        \
        _Pragma("unroll") for (int n = 0; n < 4; ++n)                        \
            BB[h][n] = *(const bf16x8*)(bp[n] + (cc) * 64 + h * 32);         \
    } while (0)

    #define COMPUTE(stage, BB) do {                                          \
        const char* _s = wlds + (stage) * 4096;                              \
        _Pragma("unroll") for (int h = 0; h < 2; ++h) {                      \
            float4 a0 = *(const float4*)(_s + offA[h][0]);                   \
            float4 a1 = *(const float4*)(_s + offA[h][1]);                   \
            bf16x8 hi, mid, lo;                                              \
            split3(a0, a1, hi, mid, lo);                                     \
            _Pragma("unroll") for (int n = 0; n < 4; ++n) {                  \
                acc[n] = MFMA_BF16(hi,  BB[h][n], acc[n], 0, 0, 0);          \
                acc[n] = MFMA_BF16(mid, BB[h][n], acc[n], 0, 0, 0);          \
                acc[n] = MFMA_BF16(lo,  BB[h][n], acc[n], 0, 0, 0);          \
            }                                                                \
        }                                                                    \
    } while (0)

    // Prologue: chunks 0,1 in flight (24 ops).
    ISSUE_W(0, 0); ISSUE_B(bX, 0);
    ISSUE_W(1, 1); ISSUE_B(bY, 1);

    #pragma unroll 1
    for (int c = 0; c < 16; c += 2) {
        WAITV12();                                  // chunk c landed
        COMPUTE(0, bX);
        ISSUE_W((c + 2) & 15, 0); ISSUE_B(bX, (c + 2) & 15);
        WAITV12();                                  // chunk c+1 landed
        COMPUTE(1, bY);
        ISSUE_W((c + 3) & 15, 1); ISSUE_B(bY, (c + 3) & 15);
    }
    // Tail prefetches wrapped to chunks 0,1 (in-bounds, unused).

    __syncthreads();   // drains vmcnt(0) -> staging LDS safe to reuse as red

    float (*red)[16][66] = reinterpret_cast<float (*)[16][66]>(lds);

    // acc -> red per verified D-map: t(col) = n*16 + r16, o = kg*4 + reg.
    #pragma unroll
    for (int r = 0; r < 4; ++r) {
        red[w][kg * 4 + r][r16]      = acc[0][r];
        red[w][kg * 4 + r][16 + r16] = acc[1][r];
        red[w][kg * 4 + r][32 + r16] = acc[2][r];
        red[w][kg * 4 + r][48 + r16] = acc[3][r];
    }
    __syncthreads();

    // Deterministic cross-wave K-reduction: each thread owns 2 (o,t) cells.
    #pragma unroll
    for (int i = tid; i < 1024; i += 512) {
        int o = i >> 6, t = i & 63;
        float s = 0.f;
        #pragma unroll
        for (int w2 = 0; w2 < 8; ++w2) s += red[w2][o][t];
        red[0][o][t] = s;
    }
    __syncthreads();

    // LIF scan: 16 threads, one neuron each, serial in t (inherent).
    if (tid < 16) {
        const int o = tid;
        float m = 0.f;
        out[o0 + o] = 0.f;                               // spike row 0
        #pragma unroll 4
        for (int t = 0; t < TSTEPS; ++t) {
            m += red[0][o][t];
            bool sp = (m >= 1.0f);
            out[(size_t)(t + 1) * NO + o0 + o] = sp ? 1.0f : 0.0f;
            m = sp ? (m - 1.0f) : m * DECAY;
        }
        out[(size_t)(TSTEPS + 1) * NO + o0 + o] = m;     // final mempot
    }
}

// ---------------------------------------------------------------------------
extern "C" void kernel_launch(void* const* d_in, const int* in_sizes, int n_in,
                              void* d_out, int out_size, void* d_ws, size_t ws_size,
                              hipStream_t stream) {
    const void*  spikes = d_in[0];
    const float* W      = (const float*)d_in[1];
    float*       out    = (float*)d_out;
    char*        ws     = (char*)d_ws;

    // ws layout: [flags 256 B][Sbf 1 MB]
    int*            flags = (int*)ws;
    unsigned short* Sbf   = (unsigned short*)(ws + 256);

    hipLaunchKernelGGL(detect_kernel,  dim3(NDET),    dim3(256), 0, stream,
                       (const unsigned int*)spikes, flags);
    hipLaunchKernelGGL(convert_kernel, dim3(256),     dim3(256), 0, stream,
                       spikes, flags, Sbf);
    hipLaunchKernelGGL(fused_kernel,   dim3(NO / 16), dim3(512), 0, stream,
                       W, Sbf, out);
}

// Round 9
// 118.124 us; speedup vs baseline: 1.4223x; 1.0891x over previous
//
#include <hip/hip_runtime.h>

#define TSTEPS 64
#define NI 8192
#define NO 8192
#define KS 8                  // K-split factor
#define KCH (NI / KS)         // 1024 k per block
#define NC (KCH / 32)         // 32 K=32 chunks per block
#define DECAY 0.9375f

typedef __attribute__((ext_vector_type(8))) short bf16x8;   // MFMA A/B frag (4 VGPR)
typedef __attribute__((ext_vector_type(4))) float f32x4;    // MFMA C/D frag

// ---------------------------------------------------------------------------
// Kernel 1: spikes -> row-major bf16 S[t][k] (1 MB), with in-block layout
// self-detection. Every block scans the SAME first-4KB window (L2-hot after
// the first block): uint8 layout has nonzero high bytes (20% density over
// 3072 candidate bytes, P(miss) ~ 0.8^3072 ~ 0); int32 layout has none.
// ---------------------------------------------------------------------------
__global__ __launch_bounds__(256) void convert_kernel(const void* sp,
                                                      unsigned short* __restrict__ Sbf) {
    __shared__ int any;
    if (threadIdx.x == 0) any = 0;
    __syncthreads();
    int local = 0;
    const unsigned int* win = (const unsigned int*)sp;   // first 4 KB, both layouts
    #pragma unroll
    for (int i = 0; i < 4; ++i) {
        unsigned int v = win[threadIdx.x * 4 + i];
        if (v & 0xFFFFFF00u) local = 1;
    }
    if (local) atomicOr(&any, 1);
    __syncthreads();
    const int f = any;                                   // 1 => uint8 layout

    const int gid = blockIdx.x * 256 + threadIdx.x;      // 0..65535
    const int t   = gid >> 10;
    const int k0  = (gid & 1023) * 8;
    unsigned h[8];
    #pragma unroll
    for (int e = 0; e < 8; ++e) {
        int gi = t * NI + k0 + e;
        bool b;
        if (f) b = ((const unsigned char*)sp)[gi] != 0;
        else   b = ((const int*)sp)[gi] != 0;
        h[e] = b ? 0x3F80u : 0u;                         // bf16(1.0) = 0x3F80
    }
    uint4 v;
    v.x = h[0] | (h[1] << 16);
    v.y = h[2] | (h[3] << 16);
    v.z = h[4] | (h[5] << 16);
    v.w = h[6] | (h[7] << 16);
    *(uint4*)(Sbf + (size_t)t * NI + k0) = v;
}

// ---------------------------------------------------------------------------
// Triple split (UNCHANGED, passing): w = hi + mid + lo, error <= 2^-22 |w|.
// ---------------------------------------------------------------------------
__device__ __forceinline__ void split3(const float4& x, const float4& y,
                                       bf16x8& hi, bf16x8& mid, bf16x8& lo) {
    float v[8] = {x.x, x.y, x.z, x.w, y.x, y.y, y.z, y.w};
    #pragma unroll
    for (int e = 0; e < 8; ++e) {
        unsigned b   = __float_as_uint(v[e]);
        unsigned hb  = b & 0xFFFF0000u;
        float    r1  = v[e] - __uint_as_float(hb);                // exact
        unsigned r1b = __float_as_uint(r1);
        unsigned mb  = r1b & 0xFFFF0000u;
        float    r2  = r1 - __uint_as_float(mb);                  // exact
        unsigned r2b = __float_as_uint(r2);
        unsigned lr  = (r2b + 0x7FFFu + ((r2b >> 16) & 1u)) >> 16; // RNE bf16
        hi[e]  = (short)(b >> 16);
        mid[e] = (short)(mb >> 16);
        lo[e]  = (short)lr;
    }
}

// ---------------------------------------------------------------------------
// Kernel 2: skinny GEMM via triple-split bf16 MFMA — round-5 structure
// (proven ~4 TB/s effective), per-wave tile halved: KS=8, OB=128.
// Grid: 128 o-blocks x 8 k-splits = 1024 blocks x 256 threads (4 blocks/CU,
// 16 waves/CU). Wave: 16 o x 64 t (1 M-tile x 4 N-tiles), acc = 16 VGPR.
// partial[kb][t][o] = sum_{k in chunk kb} W[o][k] * S[k][t]
// ---------------------------------------------------------------------------
__global__ __launch_bounds__(256, 4) void gemm_kernel(const float* __restrict__ W,
                                                      const unsigned short* __restrict__ Sbf,
                                                      float* __restrict__ partial) {
    const int lane = threadIdx.x & 63;
    const int w    = threadIdx.x >> 6;
    const int ob   = blockIdx.x & 127;  // 128 o-blocks of 64
    const int kb   = blockIdx.x >> 7;   // 8 k-splits
    const int r16  = lane & 15;
    const int kg   = lane >> 4;
    const int o0   = ob * 64 + w * 16;
    const int kbase = kb * KCH + kg * 8;

    f32x4 acc[4];
    #pragma unroll
    for (int n = 0; n < 4; ++n) acc[n] = (f32x4)0.f;

    const float* ap = W + (size_t)(o0 + r16) * NI + kbase;
    const unsigned short* bp[4];
    #pragma unroll
    for (int n = 0; n < 4; ++n)
        bp[n] = Sbf + (size_t)(n * 16 + r16) * NI + kbase;

    #pragma unroll 4
    for (int c = 0; c < NC; ++c) {
        bf16x8 Bf[4];
        #pragma unroll
        for (int n = 0; n < 4; ++n)
            Bf[n] = *(const bf16x8*)(bp[n] + c * 32);
        float4 a0 = *(const float4*)(ap + c * 32);
        float4 a1 = *(const float4*)(ap + c * 32 + 4);
        bf16x8 hi, mid, lo;
        split3(a0, a1, hi, mid, lo);
        #pragma unroll
        for (int n = 0; n < 4; ++n) {
            acc[n] = __builtin_amdgcn_mfma_f32_16x16x32_bf16(hi,  Bf[n], acc[n], 0, 0, 0);
            acc[n] = __builtin_amdgcn_mfma_f32_16x16x32_bf16(mid, Bf[n], acc[n], 0, 0, 0);
            acc[n] = __builtin_amdgcn_mfma_f32_16x16x32_bf16(lo,  Bf[n], acc[n], 0, 0, 0);
        }
    }

    // Epilogue per verified D-map: t(col) = n*16 + r16, o(row) = 4*kg + reg.
    #pragma unroll
    for (int n = 0; n < 4; ++n) {
        int t = n * 16 + r16;
        size_t off = (size_t)kb * TSTEPS * NO + (size_t)t * NO + (o0 + kg * 4);
        *(f32x4*)&partial[off] = acc[n];
    }
}

// ---------------------------------------------------------------------------
// Kernel 3 (r5 shape, KS=8): deterministic K-split reduction.
// ---------------------------------------------------------------------------
__global__ __launch_bounds__(256) void reduce_kernel(const float* __restrict__ partial,
                                                     float* __restrict__ currents) {
    int gid = blockIdx.x * 256 + threadIdx.x;   // over 64*8192
    float s = 0.f;
    #pragma unroll
    for (int kb = 0; kb < KS; ++kb) s += partial[(size_t)kb * TSTEPS * NO + gid];
    currents[gid] = s;
}

// ---------------------------------------------------------------------------
// Kernel 4 (verbatim, passing): per-neuron LIF scan.
// out = [spikes(65 x 8192) as f32 0/1, final mempot(8192)]
// ---------------------------------------------------------------------------
__global__ __launch_bounds__(256) void scan_kernel(const float* __restrict__ currents,
                                                   float* __restrict__ out) {
    int o = blockIdx.x * 256 + threadIdx.x;
    float m = 0.f;
    out[o] = 0.f;                                // spike row 0 stays zero
    for (int t = 0; t < TSTEPS; ++t) {
        m += currents[t * NO + o];
        bool sp = (m >= 1.0f);
        out[(size_t)(t + 1) * NO + o] = sp ? 1.0f : 0.0f;
        m = sp ? (m - 1.0f) : m * DECAY;
    }
    out[(size_t)(TSTEPS + 1) * NO + o] = m;      // final mempot
}

// ---------------------------------------------------------------------------
extern "C" void kernel_launch(void* const* d_in, const int* in_sizes, int n_in,
                              void* d_out, int out_size, void* d_ws, size_t ws_size,
                              hipStream_t stream) {
    const void*  spikes = d_in[0];
    const float* W      = (const float*)d_in[1];
    float*       out    = (float*)d_out;
    char*        ws     = (char*)d_ws;

    // ws layout: [Sbf 1 MB][partial 16 MB][currents 2 MB] ~= 19 MB
    unsigned short* Sbf      = (unsigned short*)ws;
    float*          partial  = (float*)(ws + (size_t)1048576);
    float*          currents = (float*)(ws + (size_t)1048576
                                           + (size_t)KS * TSTEPS * NO * 4);

    hipLaunchKernelGGL(convert_kernel, dim3(256),               dim3(256), 0, stream,
                       spikes, Sbf);
    hipLaunchKernelGGL(gemm_kernel,    dim3(128 * KS),          dim3(256), 0, stream,
                       W, Sbf, partial);
    hipLaunchKernelGGL(reduce_kernel,  dim3(TSTEPS * NO / 256), dim3(256), 0, stream,
                       partial, currents);
    hipLaunchKernelGGL(scan_kernel,    dim3(NO / 256),          dim3(256), 0, stream,
                       currents, out);
}

// Round 10
// 100.857 us; speedup vs baseline: 1.6658x; 1.1712x over previous
//
#include <hip/hip_runtime.h>

#define TSTEPS 64
#define NI 8192
#define NO 8192
#define KS 16                 // K-split factor
#define KCH (NI / KS)         // 512 k per block
#define NC (KCH / 32)         // 16 K=32 chunks per block
#define DECAY 0.9375f

typedef __attribute__((ext_vector_type(8))) short bf16x8;   // MFMA A/B frag (4 VGPR)
typedef __attribute__((ext_vector_type(4))) float f32x4;    // MFMA C/D frag

// ---------------------------------------------------------------------------
// Kernel 1 (r9's merged version, passing): spikes -> row-major bf16 S[t][k]
// (1 MB) with in-block layout self-detection on the shared first-4KB window
// (L2-hot; uint8 layout shows nonzero high bytes with P(miss) ~ 0.8^3072).
// ---------------------------------------------------------------------------
__global__ __launch_bounds__(256) void convert_kernel(const void* sp,
                                                      unsigned short* __restrict__ Sbf) {
    __shared__ int any;
    if (threadIdx.x == 0) any = 0;
    __syncthreads();
    int local = 0;
    const unsigned int* win = (const unsigned int*)sp;   // first 4 KB, both layouts
    #pragma unroll
    for (int i = 0; i < 4; ++i) {
        unsigned int v = win[threadIdx.x * 4 + i];
        if (v & 0xFFFFFF00u) local = 1;
    }
    if (local) atomicOr(&any, 1);
    __syncthreads();
    const int f = any;                                   // 1 => uint8 layout

    const int gid = blockIdx.x * 256 + threadIdx.x;      // 0..65535
    const int t   = gid >> 10;
    const int k0  = (gid & 1023) * 8;
    unsigned h[8];
    #pragma unroll
    for (int e = 0; e < 8; ++e) {
        int gi = t * NI + k0 + e;
        bool b;
        if (f) b = ((const unsigned char*)sp)[gi] != 0;
        else   b = ((const int*)sp)[gi] != 0;
        h[e] = b ? 0x3F80u : 0u;                         // bf16(1.0) = 0x3F80
    }
    uint4 v;
    v.x = h[0] | (h[1] << 16);
    v.y = h[2] | (h[3] << 16);
    v.z = h[4] | (h[5] << 16);
    v.w = h[6] | (h[7] << 16);
    *(uint4*)(Sbf + (size_t)t * NI + k0) = v;
}

// ---------------------------------------------------------------------------
// Triple split (UNCHANGED, passing): w = hi + mid + lo, error <= 2^-22 |w|.
// ---------------------------------------------------------------------------
__device__ __forceinline__ void split3(const float4& x, const float4& y,
                                       bf16x8& hi, bf16x8& mid, bf16x8& lo) {
    float v[8] = {x.x, x.y, x.z, x.w, y.x, y.y, y.z, y.w};
    #pragma unroll
    for (int e = 0; e < 8; ++e) {
        unsigned b   = __float_as_uint(v[e]);
        unsigned hb  = b & 0xFFFF0000u;
        float    r1  = v[e] - __uint_as_float(hb);                // exact
        unsigned r1b = __float_as_uint(r1);
        unsigned mb  = r1b & 0xFFFF0000u;
        float    r2  = r1 - __uint_as_float(mb);                  // exact
        unsigned r2b = __float_as_uint(r2);
        unsigned lr  = (r2b + 0x7FFFu + ((r2b >> 16) & 1u)) >> 16; // RNE bf16
        hi[e]  = (short)(b >> 16);
        mid[e] = (short)(mb >> 16);
        lo[e]  = (short)lr;
    }
}

// ---------------------------------------------------------------------------
// Kernel 2: skinny GEMM via triple-split bf16 MFMA — ROUND-5 EXACT structure
// (best measured: 100 µs total), single delta: unroll 2 -> 4 (wider load-
// hoisting window for the compiler; VGPR headroom exists under the 128 cap).
// Grid: 64 o-blocks x 16 k-splits = 1024 blocks x 256 threads (4 blocks/CU,
// 16 waves/CU = 4/SIMD). Wave: 32 o x 64 t, ~310 busy cyc/chunk -> ~1240 cyc
// latency coverage per SIMD per chunk phase.
// partial[kb][t][o] = sum_{k in chunk kb} W[o][k] * S[k][t]
// ---------------------------------------------------------------------------
__global__ __launch_bounds__(256, 4) void gemm_kernel(const float* __restrict__ W,
                                                      const unsigned short* __restrict__ Sbf,
                                                      float* __restrict__ partial) {
    const int lane = threadIdx.x & 63;
    const int w    = threadIdx.x >> 6;
    const int ob   = blockIdx.x & 63;   // 64 o-blocks of 128
    const int kb   = blockIdx.x >> 6;   // 16 k-splits
    const int r16  = lane & 15;
    const int kg   = lane >> 4;
    const int o0   = ob * 128 + w * 32;
    const int kbase = kb * KCH + kg * 8;

    f32x4 acc[2][4];
    #pragma unroll
    for (int m = 0; m < 2; ++m)
        #pragma unroll
        for (int n = 0; n < 4; ++n) acc[m][n] = (f32x4)0.f;

    const float* ap[2];
    #pragma unroll
    for (int m = 0; m < 2; ++m)
        ap[m] = W + (size_t)(o0 + m * 16 + r16) * NI + kbase;
    const unsigned short* bp[4];
    #pragma unroll
    for (int n = 0; n < 4; ++n)
        bp[n] = Sbf + (size_t)(n * 16 + r16) * NI + kbase;

    #pragma unroll 4
    for (int c = 0; c < NC; ++c) {
        bf16x8 Bf[4];
        #pragma unroll
        for (int n = 0; n < 4; ++n)
            Bf[n] = *(const bf16x8*)(bp[n] + c * 32);
        #pragma unroll
        for (int m = 0; m < 2; ++m) {
            float4 a0 = *(const float4*)(ap[m] + c * 32);
            float4 a1 = *(const float4*)(ap[m] + c * 32 + 4);
            bf16x8 hi, mid, lo;
            split3(a0, a1, hi, mid, lo);
            #pragma unroll
            for (int n = 0; n < 4; ++n) {
                acc[m][n] = __builtin_amdgcn_mfma_f32_16x16x32_bf16(
                    hi, Bf[n], acc[m][n], 0, 0, 0);
                acc[m][n] = __builtin_amdgcn_mfma_f32_16x16x32_bf16(
                    mid, Bf[n], acc[m][n], 0, 0, 0);
                acc[m][n] = __builtin_amdgcn_mfma_f32_16x16x32_bf16(
                    lo, Bf[n], acc[m][n], 0, 0, 0);
            }
        }
    }

    // Epilogue per verified D-map: t(col) = n*16 + r16, o(row) = 4*kg + reg.
    #pragma unroll
    for (int m = 0; m < 2; ++m)
        #pragma unroll
        for (int n = 0; n < 4; ++n) {
            int t = n * 16 + r16;
            size_t off = (size_t)kb * TSTEPS * NO + (size_t)t * NO
                       + (o0 + m * 16 + kg * 4);
            *(f32x4*)&partial[off] = acc[m][n];
        }
}

// ---------------------------------------------------------------------------
// Kernel 3 (verbatim r5, passing): deterministic K-split reduction.
// Full-grid (2048 blocks) so the 32 MB partial read gets chip-wide BW.
// ---------------------------------------------------------------------------
__global__ __launch_bounds__(256) void reduce_kernel(const float* __restrict__ partial,
                                                     float* __restrict__ currents) {
    int gid = blockIdx.x * 256 + threadIdx.x;   // over 64*8192
    float s = 0.f;
    #pragma unroll
    for (int kb = 0; kb < KS; ++kb) s += partial[(size_t)kb * TSTEPS * NO + gid];
    currents[gid] = s;
}

// ---------------------------------------------------------------------------
// Kernel 4 (verbatim r5, passing): per-neuron LIF scan.
// out = [spikes(65 x 8192) as f32 0/1, final mempot(8192)]
// ---------------------------------------------------------------------------
__global__ __launch_bounds__(256) void scan_kernel(const float* __restrict__ currents,
                                                   float* __restrict__ out) {
    int o = blockIdx.x * 256 + threadIdx.x;
    float m = 0.f;
    out[o] = 0.f;                                // spike row 0 stays zero
    for (int t = 0; t < TSTEPS; ++t) {
        m += currents[t * NO + o];
        bool sp = (m >= 1.0f);
        out[(size_t)(t + 1) * NO + o] = sp ? 1.0f : 0.0f;
        m = sp ? (m - 1.0f) : m * DECAY;
    }
    out[(size_t)(TSTEPS + 1) * NO + o] = m;      // final mempot
}

// ---------------------------------------------------------------------------
extern "C" void kernel_launch(void* const* d_in, const int* in_sizes, int n_in,
                              void* d_out, int out_size, void* d_ws, size_t ws_size,
                              hipStream_t stream) {
    const void*  spikes = d_in[0];
    const float* W      = (const float*)d_in[1];
    float*       out    = (float*)d_out;
    char*        ws     = (char*)d_ws;

    // ws layout: [Sbf 1 MB][partial 32 MB][currents 2 MB] ~= 35 MB
    unsigned short* Sbf      = (unsigned short*)ws;
    float*          partial  = (float*)(ws + (size_t)1048576);
    float*          currents = (float*)(ws + (size_t)1048576
                                           + (size_t)KS * TSTEPS * NO * 4);

    hipLaunchKernelGGL(convert_kernel, dim3(256),               dim3(256), 0, stream,
                       spikes, Sbf);
    hipLaunchKernelGGL(gemm_kernel,    dim3(64 * KS),           dim3(256), 0, stream,
                       W, Sbf, partial);
    hipLaunchKernelGGL(reduce_kernel,  dim3(TSTEPS * NO / 256), dim3(256), 0, stream,
                       partial, currents);
    hipLaunchKernelGGL(scan_kernel,    dim3(NO / 256),          dim3(256), 0, stream,
                       currents, out);
}